// Round 10
// baseline (78.482 us; speedup 1.0000x reference)
//
#include <hip/hip_runtime.h>
#include <hip/hip_bf16.h>

#define NS     256
#define FEAT   8192
#define BD     128
#define CD     16
#define NOUT   2048
#define OUTW   8320              // FEAT + BD
#define KSPLIT 16
#define KC     (FEAT / KSPLIT)   // 512
#define BK     64
#define NSTEP  (KC / BK)         // 8

typedef float f32x4 __attribute__((ext_vector_type(4)));
typedef short bf16x8 __attribute__((ext_vector_type(8)));
typedef short bf16x4 __attribute__((ext_vector_type(4)));
typedef unsigned int u32;

__device__ __forceinline__ bf16x4 cvt4(float a, float b, float c, float d) {
    union { __hip_bfloat162 h[2]; bf16x4 s; } u;
    u.h[0] = __float22bfloat162_rn(float2{a, b});
    u.h[1] = __float22bfloat162_rn(float2{c, d});
    return u.s;
}

__device__ __forceinline__ f32x4 bf4_to_f32(bf16x4 s) {
    f32x4 r;
    r.x = __uint_as_float(((u32)(unsigned short)s.x) << 16);
    r.y = __uint_as_float(((u32)(unsigned short)s.y) << 16);
    r.z = __uint_as_float(((u32)(unsigned short)s.z) << 16);
    r.w = __uint_as_float(((u32)(unsigned short)s.w) << 16);
    return r;
}

// -------------------------------- copy inp -> out, zero o-cols, produce Abf -
__global__ __launch_bounds__(256) void mbd_copy_kernel(const float* __restrict__ in,
                                                       float* __restrict__ out,
                                                       short* __restrict__ Abf) {
    int row = blockIdx.y;
    int c4  = blockIdx.x * 256 + threadIdx.x;
    if (c4 < 2048) {
        f32x4 v = *(const f32x4*)(in + (size_t)row * FEAT + c4 * 4);
        *(f32x4*)(out + (size_t)row * OUTW + c4 * 4) = v;
        *(bf16x4*)(Abf + (size_t)row * FEAT + c4 * 4) = cvt4(v.x, v.y, v.z, v.w);
    } else if (c4 < 2080) {
        *(f32x4*)(out + (size_t)row * OUTW + c4 * 4) = (f32x4){0.f, 0.f, 0.f, 0.f};
    }
}

// ---------------------------------------------------------------- GEMM ------
// Mt_part[kc][col][row] (bf16) = (Abf[:, kc-slice] @ T[kc-slice, :])^T.
// NO LDS, NO barriers, NO DMA: every wave is an independent 64x32x512 tile;
// stalls are per-wave and staggered, so TLP (16 waves/CU) hides latency --
// the barrier phase-lock that froze R3..R9 at ~40us is structurally gone.
// A-frag: global bf16x8, one dwordx4 per frag, 4 lane-quarters cover a full
//         64-B line per row (100% line use; A slice 256KB/kc = L2-resident).
// B-frag: 32 scalar dwords/step, each quarter-row = one full 64-B line;
//         4 waves of a block share (kc,n0) so B redundancy collapses in L1.
// Block mapping: bx&7 = XCD -> kc pair {2x,2x+1}; T slice 4MB L2-resident.
__global__ __launch_bounds__(256, 4) void mbd_gemm_kernel(const short* __restrict__ Abf,
                                                          const float* __restrict__ T,
                                                          short* __restrict__ Mt) {
    const int tid = threadIdx.x, lane = tid & 63, l15 = lane & 15, w = tid >> 6;
    const int q = lane >> 4;                   // lane quarter 0..3

    const int bx  = blockIdx.x;
    const int g   = bx >> 3;                   // 0..127 per XCD-residue
    const int kc  = (bx & 7) * 2 + (g >> 6);   // XCD x -> kc {2x,2x+1}
    const int n0  = (g & 63) * 32;             // n-window 0..2016
    const int wm  = w * 64;                    // wave's m-tile
    const int kbase = kc * KC;

    // A fragment row-pointers (q*8 bakes the lane-quarter k-offset)
    const short* ap[4];
#pragma unroll
    for (int mf = 0; mf < 4; ++mf)
        ap[mf] = Abf + (size_t)(wm + mf * 16 + l15) * FEAT + kbase + q * 8;
    // B base: lane column + lane-quarter k-offset
    const float* bp = T + ((size_t)kbase + q * 8) * NOUT + n0 + l15;

    f32x4 acc[4][2];
#pragma unroll
    for (int mf = 0; mf < 4; ++mf)
#pragma unroll
        for (int nf = 0; nf < 2; ++nf) acc[mf][nf] = (f32x4){0.f, 0.f, 0.f, 0.f};

#pragma unroll
    for (int kt = 0; kt < NSTEP; ++kt) {
        // ---- issue all of this step's loads (compiler hoists/piplines freely;
        //      no barrier anywhere to chunk the schedule)
        float br[2][2][8];
        const float* bq = bp + (size_t)kt * BK * NOUT;
#pragma unroll
        for (int h = 0; h < 2; ++h)
#pragma unroll
            for (int nf = 0; nf < 2; ++nf)
#pragma unroll
                for (int j = 0; j < 8; ++j)
                    br[h][nf][j] = bq[(size_t)(h * 32 + j) * NOUT + nf * 16];
        bf16x8 af[2][4];
#pragma unroll
        for (int h = 0; h < 2; ++h)
#pragma unroll
            for (int mf = 0; mf < 4; ++mf)
                af[h][mf] = *(const bf16x8*)(ap[mf] + kt * BK + h * 32);
        // ---- convert B, MFMA
#pragma unroll
        for (int h = 0; h < 2; ++h) {
            bf16x8 bf[2];
#pragma unroll
            for (int nf = 0; nf < 2; ++nf) {
                bf16x4 lo = cvt4(br[h][nf][0], br[h][nf][1], br[h][nf][2], br[h][nf][3]);
                bf16x4 hi = cvt4(br[h][nf][4], br[h][nf][5], br[h][nf][6], br[h][nf][7]);
                bf16x8 t;
                t[0] = lo.x; t[1] = lo.y; t[2] = lo.z; t[3] = lo.w;
                t[4] = hi.x; t[5] = hi.y; t[6] = hi.z; t[7] = hi.w;
                bf[nf] = t;
            }
#pragma unroll
            for (int mf = 0; mf < 4; ++mf)
#pragma unroll
                for (int nf = 0; nf < 2; ++nf)
                    acc[mf][nf] = __builtin_amdgcn_mfma_f32_16x16x32_bf16(
                        af[h][mf], bf[nf], acc[mf][nf], 0, 0, 0);
        }
    }

    // epilogue: C/D layout col = l&15, row = (l>>4)*4 + r  [m89-verified]
    short* Mp = Mt + (size_t)kc * NOUT * NS;
    const int r0 = q * 4;
#pragma unroll
    for (int mf = 0; mf < 4; ++mf)
#pragma unroll
        for (int nf = 0; nf < 2; ++nf) {
            int col = n0 + nf * 16 + l15;
            int row = wm + mf * 16 + r0;
            *(bf16x4*)&Mp[(size_t)col * NS + row] =
                cvt4(acc[mf][nf].x, acc[mf][nf].y, acc[mf][nf].z, acc[mf][nf].w);
        }
}

// ---------------------------------------------------------------- pairwise --
// block (b, jhalf): o_part[i,b] = sum_{j in half} exp(-sum_c |M[i,c]-M[j,c]|)
__global__ __launch_bounds__(256) void mbd_pair_kernel(const short* __restrict__ Mt,
                                                       float* __restrict__ out) {
    const int b = blockIdx.x >> 1, jh = blockIdx.x & 1;
    const int t = threadIdx.x;
    __shared__ float ldsT[CD][NS];
    __shared__ float rows[NS][20];

#pragma unroll
    for (int u4 = 0; u4 < 4; ++u4) {
        int u = t + u4 * 256;
        int c = u >> 6, r4 = (u & 63) * 4;
        f32x4 v = (f32x4){0.f, 0.f, 0.f, 0.f};
#pragma unroll
        for (int p = 0; p < KSPLIT; ++p)
            v += bf4_to_f32(*(const bf16x4*)(Mt +
                     ((size_t)p * NOUT + (size_t)b * CD + c) * NS + r4));
        *(f32x4*)&ldsT[c][r4] = v;
    }
    __syncthreads();

    float my[16];
#pragma unroll
    for (int c = 0; c < 16; ++c) my[c] = ldsT[c][t];
#pragma unroll
    for (int c = 0; c < 16; ++c) rows[t][c] = my[c];
    __syncthreads();

    float o0 = 0.f, o1 = 0.f;
    const int jbase = jh * 128;
    for (int jj = 0; jj < 128; jj += 2) {
#pragma unroll
        for (int s = 0; s < 2; ++s) {
            const float* rp = &rows[jbase + jj + s][0];
            float d0 = 0.f, d1 = 0.f, d2 = 0.f, d3 = 0.f;
#pragma unroll
            for (int qq = 0; qq < 4; ++qq) {
                f32x4 r = *(const f32x4*)(rp + qq * 4);
                d0 += fabsf(my[qq * 4 + 0] - r.x);
                d1 += fabsf(my[qq * 4 + 1] - r.y);
                d2 += fabsf(my[qq * 4 + 2] - r.z);
                d3 += fabsf(my[qq * 4 + 3] - r.w);
            }
            float d = (d0 + d1) + (d2 + d3);
            if (s == 0) o0 += __expf(-d); else o1 += __expf(-d);
        }
    }
    // exactly two addends per address -> f32 add commutative -> deterministic
    atomicAdd(&out[(size_t)t * OUTW + FEAT + b], o0 + o1);
}

// ---------------------------------------------------------------- launch ----
extern "C" void kernel_launch(void* const* d_in, const int* in_sizes, int n_in,
                              void* d_out, int out_size, void* d_ws, size_t ws_size,
                              hipStream_t stream) {
    const float* inp = (const float*)d_in[0];
    const float* T   = (const float*)d_in[1];
    float* out = (float*)d_out;

    short* Abf = (short*)d_ws;                       // 4 MiB
    short* Mt  = Abf + (size_t)NS * FEAT;            // 16 MiB

    mbd_copy_kernel<<<dim3(9, 256), 256, 0, stream>>>(inp, out, Abf);
    mbd_gemm_kernel<<<1024, 256, 0, stream>>>(Abf, T, Mt);
    mbd_pair_kernel<<<BD * 2, 256, 0, stream>>>(Mt, out);
}

// Round 11
// 78.139 us; speedup vs baseline: 1.0044x; 1.0044x over previous
//
#include <hip/hip_runtime.h>
#include <hip/hip_bf16.h>

#define NS     256
#define FEAT   8192
#define BD     128
#define CD     16
#define NOUT   2048
#define OUTW   8320              // FEAT + BD
#define KSPLIT 32
#define KC     (FEAT / KSPLIT)   // 256
#define BK     32
#define NSTEP  (KC / BK)         // 8
#define BM     128
#define BN     128

typedef float f32x4 __attribute__((ext_vector_type(4)));
typedef short bf16x8 __attribute__((ext_vector_type(8)));
typedef short bf16x4 __attribute__((ext_vector_type(4)));
typedef unsigned int u32;
typedef __attribute__((address_space(3))) u32 lds_u32;
typedef const __attribute__((address_space(1))) u32 gbl_u32;

__device__ __forceinline__ void gl_lds16(const void* g, void* l) {
    __builtin_amdgcn_global_load_lds((gbl_u32*)g, (lds_u32*)l, 16, 0, 0);
}

__device__ __forceinline__ bf16x4 cvt4(float a, float b, float c, float d) {
    union { __hip_bfloat162 h[2]; bf16x4 s; } u;
    u.h[0] = __float22bfloat162_rn(float2{a, b});
    u.h[1] = __float22bfloat162_rn(float2{c, d});
    return u.s;
}

__device__ __forceinline__ f32x4 bf4_to_f32(bf16x4 s) {
    f32x4 r;
    r.x = __uint_as_float(((u32)(unsigned short)s.x) << 16);
    r.y = __uint_as_float(((u32)(unsigned short)s.y) << 16);
    r.z = __uint_as_float(((u32)(unsigned short)s.z) << 16);
    r.w = __uint_as_float(((u32)(unsigned short)s.w) << 16);
    return r;
}

// -------------------------------- copy inp -> out, zero o-cols, produce Abf -
__global__ __launch_bounds__(256) void mbd_copy_kernel(const float* __restrict__ in,
                                                       float* __restrict__ out,
                                                       short* __restrict__ Abf) {
    int row = blockIdx.y;
    int c4  = blockIdx.x * 256 + threadIdx.x;
    if (c4 < 2048) {
        f32x4 v = *(const f32x4*)(in + (size_t)row * FEAT + c4 * 4);
        *(f32x4*)(out + (size_t)row * OUTW + c4 * 4) = v;
        *(bf16x4*)(Abf + (size_t)row * FEAT + c4 * 4) = cvt4(v.x, v.y, v.z, v.w);
    } else if (c4 < 2080) {
        *(f32x4*)(out + (size_t)row * OUTW + c4 * 4) = (f32x4){0.f, 0.f, 0.f, 0.f};
    }
}

// --------------------------------------------- transpose-cvt: Tbf[n][k] bf16 -
// 64x64 tiles; read f32x4 coalesced, LDS transpose, write bf16x8 coalesced.
__global__ __launch_bounds__(256) void mbd_tr_kernel(const float* __restrict__ T,
                                                     short* __restrict__ Tbf) {
    __shared__ short ldsT[64][72];   // [n][k], pad 8 -> 9 KB
    const int t = threadIdx.x;
    const int kt0 = (blockIdx.x >> 5) * 64;    // 128 k-tiles
    const int nt0 = (blockIdx.x & 31) * 64;    // 32  n-tiles

#pragma unroll
    for (int p = 0; p < 4; ++p) {
        int row = p * 16 + (t >> 4);           // k-row in tile
        int c4  = t & 15;                      // n-quad
        f32x4 v = *(const f32x4*)(T + (size_t)(kt0 + row) * NOUT + nt0 + c4 * 4);
        bf16x4 s = cvt4(v.x, v.y, v.z, v.w);
        ldsT[c4 * 4 + 0][row] = s.x;
        ldsT[c4 * 4 + 1][row] = s.y;
        ldsT[c4 * 4 + 2][row] = s.z;
        ldsT[c4 * 4 + 3][row] = s.w;
    }
    __syncthreads();

    const int n = t >> 2, part = t & 3;
    short* dst = Tbf + (size_t)(nt0 + n) * FEAT + kt0;
    *(bf16x8*)(dst + part * 8)       = *(const bf16x8*)&ldsT[n][part * 8];
    *(bf16x8*)(dst + (part + 4) * 8) = *(const bf16x8*)&ldsT[n][(part + 4) * 8];
}

// ---------------------------------------------------------------- GEMM ------
// Mt_part[kc][col][row] (bf16) = (Abf[:,kcslice] @ Tbf[:,kcslice]^T)^T.
// Pure-bf16 m97-shaped loop: both operands row-major-K, gl_lds16 staging with
// source-baked XOR swizzle, ds_read_b128 frags, 16 MFMA, ONE barrier/step.
// Zero VALU data work in the loop -> nothing for the compiler to serialize.
// Grid 1024 (KSPLIT=32), 32 KB LDS, launch_bounds(256,4) -> 4 blocks/CU:
// independent barrier domains overlap each other's DMA drains (m114).
__global__ __launch_bounds__(256, 4) void mbd_gemm_kernel(const short* __restrict__ Abf,
                                                          const short* __restrict__ Tbf,
                                                          short* __restrict__ Mt) {
    __shared__ __align__(16) short Als[2][BM * BK];   // 2 x 8 KB
    __shared__ __align__(16) short Bls[2][BN * BK];   // 2 x 8 KB

    const int tid = threadIdx.x, lane = tid & 63, l15 = lane & 15, w = tid >> 6;
    const int q = lane >> 4;
    const int wm = (w & 1) * 64, wn = (w >> 1) * 64;  // wave tile 64x64

    const int bx = blockIdx.x;
    const int kc = bx & 31;                  // bx%8 == kc%8 -> slabs L2-resident/XCD
    const int rest = bx >> 5;
    const int m0 = (rest & 1) * BM;
    const int n0 = (rest >> 1) * BN;
    const int kbase = kc * KC;

    // staging: 8 A-chunks + 8 B-chunks of 1 KB (16 rows x 64 B); wave owns 2+2.
    // 64-B rows: stored quad s holds logical quad s^(r&3) (baked into source).
    const short* asrc[2]; const short* bsrc[2];
    int aofs[2], bofs[2];
#pragma unroll
    for (int u = 0; u < 2; ++u) {
        const int g = w * 2 + u;                       // chunk 0..7
        const int r = lane >> 2;                       // row-in-chunk 0..15
        const int lq = (lane & 3) ^ (r & 3);           // logical quad fetched
        asrc[u] = Abf + (size_t)(m0 + g * 16 + r) * FEAT + kbase + lq * 8;
        bsrc[u] = Tbf + (size_t)(n0 + g * 16 + r) * FEAT + kbase + lq * 8;
        aofs[u] = g * 512;
        bofs[u] = g * 512;
    }

    // fragment offsets (shorts): row*32 + (q^(l15&3))*8  (row&3 == l15&3)
    const int xq = (q ^ (l15 & 3)) * 8;
    int aro[4], bro[4];
#pragma unroll
    for (int mf = 0; mf < 4; ++mf) aro[mf] = (wm + mf * 16 + l15) * BK + xq;
#pragma unroll
    for (int nf = 0; nf < 4; ++nf) bro[nf] = (wn + nf * 16 + l15) * BK + xq;

    f32x4 acc[4][4];
#pragma unroll
    for (int mf = 0; mf < 4; ++mf)
#pragma unroll
        for (int nf = 0; nf < 4; ++nf) acc[mf][nf] = (f32x4){0.f, 0.f, 0.f, 0.f};

    // prologue: stage tile 0
#pragma unroll
    for (int u = 0; u < 2; ++u) gl_lds16(asrc[u], &Als[0][aofs[u]]);
#pragma unroll
    for (int u = 0; u < 2; ++u) gl_lds16(bsrc[u], &Bls[0][bofs[u]]);
    __syncthreads();

    for (int kt = 0; kt < NSTEP; ++kt) {
        const int cur = kt & 1;
        if (kt + 1 < NSTEP) {   // fire-and-forget DMA into other buffer
#pragma unroll
            for (int u = 0; u < 2; ++u)
                gl_lds16(asrc[u] + (kt + 1) * BK, &Als[cur ^ 1][aofs[u]]);
#pragma unroll
            for (int u = 0; u < 2; ++u)
                gl_lds16(bsrc[u] + (kt + 1) * BK, &Bls[cur ^ 1][bofs[u]]);
        }
        bf16x8 af[4], bf[4];
#pragma unroll
        for (int mf = 0; mf < 4; ++mf) af[mf] = *(const bf16x8*)&Als[cur][aro[mf]];
#pragma unroll
        for (int nf = 0; nf < 4; ++nf) bf[nf] = *(const bf16x8*)&Bls[cur][bro[nf]];
        __builtin_amdgcn_s_setprio(1);
#pragma unroll
        for (int mf = 0; mf < 4; ++mf)
#pragma unroll
            for (int nf = 0; nf < 4; ++nf)
                acc[mf][nf] = __builtin_amdgcn_mfma_f32_16x16x32_bf16(
                    af[mf], bf[nf], acc[mf][nf], 0, 0, 0);
        __builtin_amdgcn_s_setprio(0);
        if (kt + 1 < NSTEP) __syncthreads();   // drains DMA; dbuf swap safe
    }

    // epilogue: C/D layout col = l&15, row = (l>>4)*4 + r  [m89-verified]
    short* Mp = Mt + (size_t)kc * NOUT * NS;
    const int r0 = q * 4;
#pragma unroll
    for (int mf = 0; mf < 4; ++mf)
#pragma unroll
        for (int nf = 0; nf < 4; ++nf) {
            int col = n0 + wn + nf * 16 + l15;
            int row = m0 + wm + mf * 16 + r0;
            *(bf16x4*)&Mp[(size_t)col * NS + row] =
                cvt4(acc[mf][nf].x, acc[mf][nf].y, acc[mf][nf].z, acc[mf][nf].w);
        }
}

// ---------------------------------------------------------------- pairwise --
// block (b, jhalf): o_part[i,b] = sum_{j in half} exp(-sum_c |M[i,c]-M[j,c]|)
__global__ __launch_bounds__(256) void mbd_pair_kernel(const short* __restrict__ Mt,
                                                       float* __restrict__ out) {
    const int b = blockIdx.x >> 1, jh = blockIdx.x & 1;
    const int t = threadIdx.x;
    __shared__ float ldsT[CD][NS];
    __shared__ float rows[NS][20];

#pragma unroll
    for (int u4 = 0; u4 < 4; ++u4) {
        int u = t + u4 * 256;
        int c = u >> 6, r4 = (u & 63) * 4;
        f32x4 v = (f32x4){0.f, 0.f, 0.f, 0.f};
        for (int p = 0; p < KSPLIT; ++p)
            v += bf4_to_f32(*(const bf16x4*)(Mt +
                     ((size_t)p * NOUT + (size_t)b * CD + c) * NS + r4));
        *(f32x4*)&ldsT[c][r4] = v;
    }
    __syncthreads();

    float my[16];
#pragma unroll
    for (int c = 0; c < 16; ++c) my[c] = ldsT[c][t];
#pragma unroll
    for (int c = 0; c < 16; ++c) rows[t][c] = my[c];
    __syncthreads();

    float o0 = 0.f, o1 = 0.f;
    const int jbase = jh * 128;
    for (int jj = 0; jj < 128; jj += 2) {
#pragma unroll
        for (int s = 0; s < 2; ++s) {
            const float* rp = &rows[jbase + jj + s][0];
            float d0 = 0.f, d1 = 0.f, d2 = 0.f, d3 = 0.f;
#pragma unroll
            for (int qq = 0; qq < 4; ++qq) {
                f32x4 r = *(const f32x4*)(rp + qq * 4);
                d0 += fabsf(my[qq * 4 + 0] - r.x);
                d1 += fabsf(my[qq * 4 + 1] - r.y);
                d2 += fabsf(my[qq * 4 + 2] - r.z);
                d3 += fabsf(my[qq * 4 + 3] - r.w);
            }
            float d = (d0 + d1) + (d2 + d3);
            if (s == 0) o0 += __expf(-d); else o1 += __expf(-d);
        }
    }
    // exactly two addends per address -> f32 add commutative -> deterministic
    atomicAdd(&out[(size_t)t * OUTW + FEAT + b], o0 + o1);
}

// ---------------------------------------------------------------- launch ----
extern "C" void kernel_launch(void* const* d_in, const int* in_sizes, int n_in,
                              void* d_out, int out_size, void* d_ws, size_t ws_size,
                              hipStream_t stream) {
    const float* inp = (const float*)d_in[0];
    const float* T   = (const float*)d_in[1];
    float* out = (float*)d_out;

    // ws: Abf 4 MiB | Mt 33.5 MiB (32 partials) | Tbf 33.5 MiB  (= 71 MiB,
    // ws_size is ~256 MiB per the harness fill counters)
    short* Abf = (short*)d_ws;
    short* Mt  = Abf + (size_t)NS * FEAT;                 // 2,097,152 shorts in
    short* Tbf = Mt + (size_t)KSPLIT * NOUT * NS;         // +16,777,216 shorts

    mbd_copy_kernel<<<dim3(9, 256), 256, 0, stream>>>(inp, out, Abf);
    mbd_tr_kernel<<<4096, 256, 0, stream>>>(T, Tbf);
    mbd_gemm_kernel<<<1024, 256, 0, stream>>>(Abf, Tbf, Mt);
    mbd_pair_kernel<<<BD * 2, 256, 0, stream>>>(Mt, out);
}

// Round 12
// 71.217 us; speedup vs baseline: 1.1020x; 1.0972x over previous
//
#include <hip/hip_runtime.h>
#include <hip/hip_bf16.h>

#define NS     256
#define FEAT   8192
#define BD     128
#define CD     16
#define NOUT   2048
#define OUTW   8320              // FEAT + BD
#define KSPLIT 16
#define KC     (FEAT / KSPLIT)   // 512
#define BK     32
#define NSTEP  (KC / BK)         // 16
#define BM     128
#define BN     128

typedef float f32x4 __attribute__((ext_vector_type(4)));
typedef short bf16x8 __attribute__((ext_vector_type(8)));
typedef short bf16x4 __attribute__((ext_vector_type(4)));
typedef unsigned int u32;
typedef __attribute__((address_space(3))) u32 lds_u32;
typedef const __attribute__((address_space(1))) u32 gbl_u32;

__device__ __forceinline__ void gl_lds16(const void* g, void* l) {
    __builtin_amdgcn_global_load_lds((gbl_u32*)g, (lds_u32*)l, 16, 0, 0);
}

__device__ __forceinline__ bf16x4 cvt4(float a, float b, float c, float d) {
    union { __hip_bfloat162 h[2]; bf16x4 s; } u;
    u.h[0] = __float22bfloat162_rn(float2{a, b});
    u.h[1] = __float22bfloat162_rn(float2{c, d});
    return u.s;
}

__device__ __forceinline__ f32x4 bf4_to_f32(bf16x4 s) {
    f32x4 r;
    r.x = __uint_as_float(((u32)(unsigned short)s.x) << 16);
    r.y = __uint_as_float(((u32)(unsigned short)s.y) << 16);
    r.z = __uint_as_float(((u32)(unsigned short)s.z) << 16);
    r.w = __uint_as_float(((u32)(unsigned short)s.w) << 16);
    return r;
}

// -------------------------------- copy inp -> out, zero o-cols, produce Abf -
__global__ __launch_bounds__(256) void mbd_copy_kernel(const float* __restrict__ in,
                                                       float* __restrict__ out,
                                                       short* __restrict__ Abf) {
    int row = blockIdx.y;
    int c4  = blockIdx.x * 256 + threadIdx.x;
    if (c4 < 2048) {
        f32x4 v = *(const f32x4*)(in + (size_t)row * FEAT + c4 * 4);
        *(f32x4*)(out + (size_t)row * OUTW + c4 * 4) = v;
        *(bf16x4*)(Abf + (size_t)row * FEAT + c4 * 4) = cvt4(v.x, v.y, v.z, v.w);
    } else if (c4 < 2080) {
        *(f32x4*)(out + (size_t)row * OUTW + c4 * 4) = (f32x4){0.f, 0.f, 0.f, 0.f};
    }
}

// --------------------------------------------- transpose-cvt: Tbf[n][k] bf16 -
// 64x64 tiles; read f32x4 coalesced, LDS transpose, write bf16x8 coalesced.
__global__ __launch_bounds__(256) void mbd_tr_kernel(const float* __restrict__ T,
                                                     short* __restrict__ Tbf) {
    __shared__ short ldsT[64][72];   // [n][k], pad 8 -> 9 KB
    const int t = threadIdx.x;
    const int kt0 = (blockIdx.x >> 5) * 64;    // 128 k-tiles
    const int nt0 = (blockIdx.x & 31) * 64;    // 32  n-tiles

#pragma unroll
    for (int p = 0; p < 4; ++p) {
        int row = p * 16 + (t >> 4);           // k-row in tile
        int c4  = t & 15;                      // n-quad
        f32x4 v = *(const f32x4*)(T + (size_t)(kt0 + row) * NOUT + nt0 + c4 * 4);
        bf16x4 s = cvt4(v.x, v.y, v.z, v.w);
        ldsT[c4 * 4 + 0][row] = s.x;
        ldsT[c4 * 4 + 1][row] = s.y;
        ldsT[c4 * 4 + 2][row] = s.z;
        ldsT[c4 * 4 + 3][row] = s.w;
    }
    __syncthreads();

    const int n = t >> 2, part = t & 3;
    short* dst = Tbf + (size_t)(nt0 + n) * FEAT + kt0;
    *(bf16x8*)(dst + part * 8)       = *(const bf16x8*)&ldsT[n][part * 8];
    *(bf16x8*)(dst + (part + 4) * 8) = *(const bf16x8*)&ldsT[n][(part + 4) * 8];
}

// ---------------------------------------------------------------- GEMM ------
// Mt_part[kc][col][row] (bf16) = (Abf[:,kcslice] @ Tbf[:,kcslice]^T)^T.
// Pure-bf16 m97-shaped loop (R11-verified): both operands row-major-K,
// gl_lds16 staging with source-baked XOR swizzle, ds_read_b128 frags,
// 16 MFMA, ONE barrier/step, zero in-loop VALU data work.
// KSPLIT=16 -> grid 512 = 2 blocks/CU (independent barrier domains, m114).
__global__ __launch_bounds__(256, 4) void mbd_gemm_kernel(const short* __restrict__ Abf,
                                                          const short* __restrict__ Tbf,
                                                          short* __restrict__ Mt) {
    __shared__ __align__(16) short Als[2][BM * BK];   // 2 x 8 KB
    __shared__ __align__(16) short Bls[2][BN * BK];   // 2 x 8 KB

    const int tid = threadIdx.x, lane = tid & 63, l15 = lane & 15, w = tid >> 6;
    const int q = lane >> 4;
    const int wm = (w & 1) * 64, wn = (w >> 1) * 64;  // wave tile 64x64

    const int bx = blockIdx.x;
    const int kc = bx & 15;                  // bx%8 == kc%8 -> slabs L2-resident/XCD
    const int rest = bx >> 4;
    const int m0 = (rest & 1) * BM;
    const int n0 = (rest >> 1) * BN;
    const int kbase = kc * KC;

    // staging: 8 A-chunks + 8 B-chunks of 1 KB (16 rows x 64 B); wave owns 2+2.
    // 64-B rows: stored quad s holds logical quad s^(r&3) (baked into source).
    const short* asrc[2]; const short* bsrc[2];
    int aofs[2], bofs[2];
#pragma unroll
    for (int u = 0; u < 2; ++u) {
        const int g = w * 2 + u;                       // chunk 0..7
        const int r = lane >> 2;                       // row-in-chunk 0..15
        const int lq = (lane & 3) ^ (r & 3);           // logical quad fetched
        asrc[u] = Abf + (size_t)(m0 + g * 16 + r) * FEAT + kbase + lq * 8;
        bsrc[u] = Tbf + (size_t)(n0 + g * 16 + r) * FEAT + kbase + lq * 8;
        aofs[u] = g * 512;
        bofs[u] = g * 512;
    }

    // fragment offsets (shorts): row*32 + (q^(l15&3))*8
    const int xq = (q ^ (l15 & 3)) * 8;
    int aro[4], bro[4];
#pragma unroll
    for (int mf = 0; mf < 4; ++mf) aro[mf] = (wm + mf * 16 + l15) * BK + xq;
#pragma unroll
    for (int nf = 0; nf < 4; ++nf) bro[nf] = (wn + nf * 16 + l15) * BK + xq;

    f32x4 acc[4][4];
#pragma unroll
    for (int mf = 0; mf < 4; ++mf)
#pragma unroll
        for (int nf = 0; nf < 4; ++nf) acc[mf][nf] = (f32x4){0.f, 0.f, 0.f, 0.f};

    // prologue: stage tile 0
#pragma unroll
    for (int u = 0; u < 2; ++u) gl_lds16(asrc[u], &Als[0][aofs[u]]);
#pragma unroll
    for (int u = 0; u < 2; ++u) gl_lds16(bsrc[u], &Bls[0][bofs[u]]);
    __syncthreads();

    for (int kt = 0; kt < NSTEP; ++kt) {
        const int cur = kt & 1;
        if (kt + 1 < NSTEP) {   // fire-and-forget DMA into other buffer
#pragma unroll
            for (int u = 0; u < 2; ++u)
                gl_lds16(asrc[u] + (kt + 1) * BK, &Als[cur ^ 1][aofs[u]]);
#pragma unroll
            for (int u = 0; u < 2; ++u)
                gl_lds16(bsrc[u] + (kt + 1) * BK, &Bls[cur ^ 1][bofs[u]]);
        }
        bf16x8 af[4], bf[4];
#pragma unroll
        for (int mf = 0; mf < 4; ++mf) af[mf] = *(const bf16x8*)&Als[cur][aro[mf]];
#pragma unroll
        for (int nf = 0; nf < 4; ++nf) bf[nf] = *(const bf16x8*)&Bls[cur][bro[nf]];
        __builtin_amdgcn_s_setprio(1);
#pragma unroll
        for (int mf = 0; mf < 4; ++mf)
#pragma unroll
            for (int nf = 0; nf < 4; ++nf)
                acc[mf][nf] = __builtin_amdgcn_mfma_f32_16x16x32_bf16(
                    af[mf], bf[nf], acc[mf][nf], 0, 0, 0);
        __builtin_amdgcn_s_setprio(0);
        if (kt + 1 < NSTEP) __syncthreads();   // drains DMA; dbuf swap safe
    }

    // epilogue: C/D layout col = l&15, row = (l>>4)*4 + r  [m89-verified]
    short* Mp = Mt + (size_t)kc * NOUT * NS;
    const int r0 = q * 4;
#pragma unroll
    for (int mf = 0; mf < 4; ++mf)
#pragma unroll
        for (int nf = 0; nf < 4; ++nf) {
            int col = n0 + wn + nf * 16 + l15;
            int row = m0 + wm + mf * 16 + r0;
            *(bf16x4*)&Mp[(size_t)col * NS + row] =
                cvt4(acc[mf][nf].x, acc[mf][nf].y, acc[mf][nf].z, acc[mf][nf].w);
        }
}

// ------------------------------------------------- reduce 16 partials -> Msum
// Msum[col][row] bf16 = sum_p Mt[p][col][row]. 65536 threads, each one bf16x8
// chunk over all 16 partials (compile-time strides -> 16 outstanding dwordx4).
__global__ __launch_bounds__(256) void mbd_reduce_kernel(const short* __restrict__ Mt,
                                                         short* __restrict__ Msum) {
    const int gid = blockIdx.x * 256 + threadIdx.x;   // 0..65535
    const int col = gid >> 5;
    const int r8  = (gid & 31) * 8;
    f32x4 lo = (f32x4){0.f, 0.f, 0.f, 0.f}, hi = lo;
#pragma unroll
    for (int p = 0; p < KSPLIT; ++p) {
        bf16x8 v = *(const bf16x8*)(Mt + ((size_t)p * NOUT + col) * NS + r8);
        bf16x4 a, b;
        a.x = v[0]; a.y = v[1]; a.z = v[2]; a.w = v[3];
        b.x = v[4]; b.y = v[5]; b.z = v[6]; b.w = v[7];
        lo += bf4_to_f32(a);
        hi += bf4_to_f32(b);
    }
    bf16x4 slo = cvt4(lo.x, lo.y, lo.z, lo.w);
    bf16x4 shi = cvt4(hi.x, hi.y, hi.z, hi.w);
    bf16x8 s;
    s[0] = slo.x; s[1] = slo.y; s[2] = slo.z; s[3] = slo.w;
    s[4] = shi.x; s[5] = shi.y; s[6] = shi.z; s[7] = shi.w;
    *(bf16x8*)(Msum + (size_t)col * NS + r8) = s;
}

// ---------------------------------------------------------------- pairwise --
// block (b, jhalf): o_part[i,b] = sum_{j in half} exp(-sum_c |M[i,c]-M[j,c]|)
// Msum layout [col][row] bf16; per-block slice = 8 KB (L2-hit).
__global__ __launch_bounds__(256) void mbd_pair_kernel(const short* __restrict__ Msum,
                                                       float* __restrict__ out) {
    const int b = blockIdx.x >> 1, jh = blockIdx.x & 1;
    const int t = threadIdx.x;
    __shared__ float ldsT[CD][NS];
    __shared__ float rows[NS][20];

#pragma unroll
    for (int u = 0; u < 2; ++u) {
        int chunk = t * 2 + u;                 // 0..511 (16 c x 32 row-chunks)
        int c  = chunk >> 5;
        int r8 = (chunk & 31) * 8;
        bf16x8 v = *(const bf16x8*)(Msum + (size_t)(b * CD + c) * NS + r8);
        bf16x4 a, d;
        a.x = v[0]; a.y = v[1]; a.z = v[2]; a.w = v[3];
        d.x = v[4]; d.y = v[5]; d.z = v[6]; d.w = v[7];
        *(f32x4*)&ldsT[c][r8]     = bf4_to_f32(a);
        *(f32x4*)&ldsT[c][r8 + 4] = bf4_to_f32(d);
    }
    __syncthreads();

    float my[16];
#pragma unroll
    for (int c = 0; c < 16; ++c) my[c] = ldsT[c][t];
#pragma unroll
    for (int c = 0; c < 16; ++c) rows[t][c] = my[c];
    __syncthreads();

    float o0 = 0.f, o1 = 0.f;
    const int jbase = jh * 128;
    for (int jj = 0; jj < 128; jj += 2) {
#pragma unroll
        for (int s = 0; s < 2; ++s) {
            const float* rp = &rows[jbase + jj + s][0];
            float d0 = 0.f, d1 = 0.f, d2 = 0.f, d3 = 0.f;
#pragma unroll
            for (int qq = 0; qq < 4; ++qq) {
                f32x4 r = *(const f32x4*)(rp + qq * 4);
                d0 += fabsf(my[qq * 4 + 0] - r.x);
                d1 += fabsf(my[qq * 4 + 1] - r.y);
                d2 += fabsf(my[qq * 4 + 2] - r.z);
                d3 += fabsf(my[qq * 4 + 3] - r.w);
            }
            float d = (d0 + d1) + (d2 + d3);
            if (s == 0) o0 += __expf(-d); else o1 += __expf(-d);
        }
    }
    // exactly two addends per address -> f32 add commutative -> deterministic
    atomicAdd(&out[(size_t)t * OUTW + FEAT + b], o0 + o1);
}

// ---------------------------------------------------------------- launch ----
extern "C" void kernel_launch(void* const* d_in, const int* in_sizes, int n_in,
                              void* d_out, int out_size, void* d_ws, size_t ws_size,
                              hipStream_t stream) {
    const float* inp = (const float*)d_in[0];
    const float* T   = (const float*)d_in[1];
    float* out = (float*)d_out;

    // ws: Abf 4 MiB | Mt 16.75 MiB | Tbf 33.5 MiB | Msum 1 MiB  (~55 MiB)
    short* Abf  = (short*)d_ws;
    short* Mt   = Abf + (size_t)NS * FEAT;                 // +4 MiB
    short* Tbf  = Mt + (size_t)KSPLIT * NOUT * NS;         // +16.75 MiB
    short* Msum = Tbf + (size_t)NOUT * FEAT;               // +33.5 MiB

    mbd_copy_kernel<<<dim3(9, 256), 256, 0, stream>>>(inp, out, Abf);
    mbd_tr_kernel<<<4096, 256, 0, stream>>>(T, Tbf);
    mbd_gemm_kernel<<<512, 256, 0, stream>>>(Abf, Tbf, Mt);
    mbd_reduce_kernel<<<256, 256, 0, stream>>>(Mt, Msum);
    mbd_pair_kernel<<<BD * 2, 256, 0, stream>>>(Msum, out);
}

// Round 13
// 68.979 us; speedup vs baseline: 1.1378x; 1.0325x over previous
//
#include <hip/hip_runtime.h>
#include <hip/hip_bf16.h>

#define NS     256
#define FEAT   8192
#define BD     128
#define CD     16
#define NOUT   2048
#define OUTW   8320              // FEAT + BD
#define KSPLIT 16
#define KC     (FEAT / KSPLIT)   // 512
#define BK     32
#define NSTEP  (KC / BK)         // 16
#define BM     128
#define BN     128

typedef float f32x4 __attribute__((ext_vector_type(4)));
typedef short bf16x8 __attribute__((ext_vector_type(8)));
typedef short bf16x4 __attribute__((ext_vector_type(4)));
typedef unsigned int u32;
typedef __attribute__((address_space(3))) u32 lds_u32;
typedef const __attribute__((address_space(1))) u32 gbl_u32;

__device__ __forceinline__ void gl_lds16(const void* g, void* l) {
    __builtin_amdgcn_global_load_lds((gbl_u32*)g, (lds_u32*)l, 16, 0, 0);
}

__device__ __forceinline__ bf16x4 cvt4(float a, float b, float c, float d) {
    union { __hip_bfloat162 h[2]; bf16x4 s; } u;
    u.h[0] = __float22bfloat162_rn(float2{a, b});
    u.h[1] = __float22bfloat162_rn(float2{c, d});
    return u.s;
}

__device__ __forceinline__ f32x4 bf4_to_f32(bf16x4 s) {
    f32x4 r;
    r.x = __uint_as_float(((u32)(unsigned short)s.x) << 16);
    r.y = __uint_as_float(((u32)(unsigned short)s.y) << 16);
    r.z = __uint_as_float(((u32)(unsigned short)s.z) << 16);
    r.w = __uint_as_float(((u32)(unsigned short)s.w) << 16);
    return r;
}

// ------------------------------------------------------------- prep (fused) -
// blocks 0..2303:    copy inp -> out rows, zero o-cols, produce Abf bf16
// blocks 2304..6399: transpose-cvt T f32 [k][n] -> Tbf bf16 [n][k] (64x64 tile)
// Independent streaming workloads in ONE grid -> they overlap instead of
// serializing across a launch boundary.
__global__ __launch_bounds__(256) void mbd_prep_kernel(const float* __restrict__ in,
                                                       float* __restrict__ out,
                                                       short* __restrict__ Abf,
                                                       const float* __restrict__ T,
                                                       short* __restrict__ Tbf) {
    __shared__ short ldsT[64][72];   // tr scratch (copy blocks ignore it)
    const int bx = blockIdx.x, t = threadIdx.x;

    if (bx < 2304) {                 // ---- copy part (256 rows x 9 chunks)
        const int row = bx / 9;
        const int c4  = (bx - row * 9) * 256 + t;
        if (c4 < 2048) {
            f32x4 v = *(const f32x4*)(in + (size_t)row * FEAT + c4 * 4);
            *(f32x4*)(out + (size_t)row * OUTW + c4 * 4) = v;
            *(bf16x4*)(Abf + (size_t)row * FEAT + c4 * 4) = cvt4(v.x, v.y, v.z, v.w);
        } else if (c4 < 2080) {
            *(f32x4*)(out + (size_t)row * OUTW + c4 * 4) = (f32x4){0.f, 0.f, 0.f, 0.f};
        }
        return;
    }

    // ---- transpose part
    const int b2  = bx - 2304;                 // 0..4095
    const int kt0 = (b2 >> 5) * 64;            // 128 k-tiles
    const int nt0 = (b2 & 31) * 64;            // 32  n-tiles

#pragma unroll
    for (int p = 0; p < 4; ++p) {
        int row = p * 16 + (t >> 4);           // k-row in tile
        int c4  = t & 15;                      // n-quad
        f32x4 v = *(const f32x4*)(T + (size_t)(kt0 + row) * NOUT + nt0 + c4 * 4);
        bf16x4 s = cvt4(v.x, v.y, v.z, v.w);
        ldsT[c4 * 4 + 0][row] = s.x;
        ldsT[c4 * 4 + 1][row] = s.y;
        ldsT[c4 * 4 + 2][row] = s.z;
        ldsT[c4 * 4 + 3][row] = s.w;
    }
    __syncthreads();

    const int n = t >> 2, part = t & 3;
    short* dst = Tbf + (size_t)(nt0 + n) * FEAT + kt0;
    *(bf16x8*)(dst + part * 8)       = *(const bf16x8*)&ldsT[n][part * 8];
    *(bf16x8*)(dst + (part + 4) * 8) = *(const bf16x8*)&ldsT[n][(part + 4) * 8];
}

// ---------------------------------------------------------------- GEMM ------
// Mt_part[kc][col][row] (bf16) = (Abf[:,kcslice] @ Tbf[:,kcslice]^T)^T.
// R11/R12-verified pure-bf16 loop: both operands row-major-K, gl_lds16
// staging with source-baked XOR swizzle, ds_read_b128 frags, 16 MFMA,
// ONE barrier/step, zero in-loop VALU data work. Grid 512 = 2 blocks/CU.
__global__ __launch_bounds__(256, 4) void mbd_gemm_kernel(const short* __restrict__ Abf,
                                                          const short* __restrict__ Tbf,
                                                          short* __restrict__ Mt) {
    __shared__ __align__(16) short Als[2][BM * BK];   // 2 x 8 KB
    __shared__ __align__(16) short Bls[2][BN * BK];   // 2 x 8 KB

    const int tid = threadIdx.x, lane = tid & 63, l15 = lane & 15, w = tid >> 6;
    const int q = lane >> 4;
    const int wm = (w & 1) * 64, wn = (w >> 1) * 64;  // wave tile 64x64

    const int bx = blockIdx.x;
    const int kc = bx & 15;                  // bx%8 == kc%8 -> slabs L2-resident/XCD
    const int rest = bx >> 4;
    const int m0 = (rest & 1) * BM;
    const int n0 = (rest >> 1) * BN;
    const int kbase = kc * KC;

    const short* asrc[2]; const short* bsrc[2];
    int aofs[2], bofs[2];
#pragma unroll
    for (int u = 0; u < 2; ++u) {
        const int g = w * 2 + u;                       // chunk 0..7
        const int r = lane >> 2;                       // row-in-chunk 0..15
        const int lq = (lane & 3) ^ (r & 3);           // source-baked XOR swizzle
        asrc[u] = Abf + (size_t)(m0 + g * 16 + r) * FEAT + kbase + lq * 8;
        bsrc[u] = Tbf + (size_t)(n0 + g * 16 + r) * FEAT + kbase + lq * 8;
        aofs[u] = g * 512;
        bofs[u] = g * 512;
    }

    const int xq = (q ^ (l15 & 3)) * 8;
    int aro[4], bro[4];
#pragma unroll
    for (int mf = 0; mf < 4; ++mf) aro[mf] = (wm + mf * 16 + l15) * BK + xq;
#pragma unroll
    for (int nf = 0; nf < 4; ++nf) bro[nf] = (wn + nf * 16 + l15) * BK + xq;

    f32x4 acc[4][4];
#pragma unroll
    for (int mf = 0; mf < 4; ++mf)
#pragma unroll
        for (int nf = 0; nf < 4; ++nf) acc[mf][nf] = (f32x4){0.f, 0.f, 0.f, 0.f};

#pragma unroll
    for (int u = 0; u < 2; ++u) gl_lds16(asrc[u], &Als[0][aofs[u]]);
#pragma unroll
    for (int u = 0; u < 2; ++u) gl_lds16(bsrc[u], &Bls[0][bofs[u]]);
    __syncthreads();

    for (int kt = 0; kt < NSTEP; ++kt) {
        const int cur = kt & 1;
        if (kt + 1 < NSTEP) {   // fire-and-forget DMA into other buffer
#pragma unroll
            for (int u = 0; u < 2; ++u)
                gl_lds16(asrc[u] + (kt + 1) * BK, &Als[cur ^ 1][aofs[u]]);
#pragma unroll
            for (int u = 0; u < 2; ++u)
                gl_lds16(bsrc[u] + (kt + 1) * BK, &Bls[cur ^ 1][bofs[u]]);
        }
        bf16x8 af[4], bf[4];
#pragma unroll
        for (int mf = 0; mf < 4; ++mf) af[mf] = *(const bf16x8*)&Als[cur][aro[mf]];
#pragma unroll
        for (int nf = 0; nf < 4; ++nf) bf[nf] = *(const bf16x8*)&Bls[cur][bro[nf]];
        __builtin_amdgcn_s_setprio(1);
#pragma unroll
        for (int mf = 0; mf < 4; ++mf)
#pragma unroll
            for (int nf = 0; nf < 4; ++nf)
                acc[mf][nf] = __builtin_amdgcn_mfma_f32_16x16x32_bf16(
                    af[mf], bf[nf], acc[mf][nf], 0, 0, 0);
        __builtin_amdgcn_s_setprio(0);
        if (kt + 1 < NSTEP) __syncthreads();   // drains DMA; dbuf swap safe
    }

    // epilogue: C/D layout col = l&15, row = (l>>4)*4 + r  [m89-verified]
    short* Mp = Mt + (size_t)kc * NOUT * NS;
    const int r0 = q * 4;
#pragma unroll
    for (int mf = 0; mf < 4; ++mf)
#pragma unroll
        for (int nf = 0; nf < 4; ++nf) {
            int col = n0 + wn + nf * 16 + l15;
            int row = m0 + wm + mf * 16 + r0;
            *(bf16x4*)&Mp[(size_t)col * NS + row] =
                cvt4(acc[mf][nf].x, acc[mf][nf].y, acc[mf][nf].z, acc[mf][nf].w);
        }
}

// ---------------------------------------------------- pairwise (fused fold) -
// block (b, jhalf): o_part[i,b] = sum_{j in half} exp(-sum_c |M[i,c]-M[j,c]|).
// Fold of the 16 Mt partials is done inline with the reduce-kernel access
// pattern (bf16x8, compile-time strides, 32 outstanding loads/thread) -- NOT
// R11's scattered 8-B loads. Sums in f32 (better than R12's bf16 Msum hop).
__global__ __launch_bounds__(256) void mbd_pair_kernel(const short* __restrict__ Mt,
                                                       float* __restrict__ out) {
    const int b = blockIdx.x >> 1, jh = blockIdx.x & 1;
    const int t = threadIdx.x;
    __shared__ float ldsT[CD][NS];
    __shared__ float rows[NS][20];

#pragma unroll
    for (int u = 0; u < 2; ++u) {
        int chunk = t * 2 + u;                 // 0..511 (16 c x 32 row-chunks)
        int c  = chunk >> 5;
        int r8 = (chunk & 31) * 8;
        f32x4 lo = (f32x4){0.f, 0.f, 0.f, 0.f}, hi = lo;
#pragma unroll
        for (int p = 0; p < KSPLIT; ++p) {
            bf16x8 v = *(const bf16x8*)(Mt + ((size_t)p * NOUT + b * CD + c) * NS + r8);
            bf16x4 a, d;
            a.x = v[0]; a.y = v[1]; a.z = v[2]; a.w = v[3];
            d.x = v[4]; d.y = v[5]; d.z = v[6]; d.w = v[7];
            lo += bf4_to_f32(a);
            hi += bf4_to_f32(d);
        }
        *(f32x4*)&ldsT[c][r8]     = lo;
        *(f32x4*)&ldsT[c][r8 + 4] = hi;
    }
    __syncthreads();

    float my[16];
#pragma unroll
    for (int c = 0; c < 16; ++c) my[c] = ldsT[c][t];
#pragma unroll
    for (int c = 0; c < 16; ++c) rows[t][c] = my[c];
    __syncthreads();

    float o0 = 0.f, o1 = 0.f;
    const int jbase = jh * 128;
    for (int jj = 0; jj < 128; jj += 2) {
#pragma unroll
        for (int s = 0; s < 2; ++s) {
            const float* rp = &rows[jbase + jj + s][0];
            float d0 = 0.f, d1 = 0.f, d2 = 0.f, d3 = 0.f;
#pragma unroll
            for (int qq = 0; qq < 4; ++qq) {
                f32x4 r = *(const f32x4*)(rp + qq * 4);
                d0 += fabsf(my[qq * 4 + 0] - r.x);
                d1 += fabsf(my[qq * 4 + 1] - r.y);
                d2 += fabsf(my[qq * 4 + 2] - r.z);
                d3 += fabsf(my[qq * 4 + 3] - r.w);
            }
            float d = (d0 + d1) + (d2 + d3);
            if (s == 0) o0 += __expf(-d); else o1 += __expf(-d);
        }
    }
    // exactly two addends per address -> f32 add commutative -> deterministic
    atomicAdd(&out[(size_t)t * OUTW + FEAT + b], o0 + o1);
}

// ---------------------------------------------------------------- launch ----
extern "C" void kernel_launch(void* const* d_in, const int* in_sizes, int n_in,
                              void* d_out, int out_size, void* d_ws, size_t ws_size,
                              hipStream_t stream) {
    const float* inp = (const float*)d_in[0];
    const float* T   = (const float*)d_in[1];
    float* out = (float*)d_out;

    // ws: Abf 4 MiB | Mt 16 MiB | Tbf 32 MiB  (~52 MiB)
    short* Abf = (short*)d_ws;
    short* Mt  = Abf + (size_t)NS * FEAT;
    short* Tbf = Mt + (size_t)KSPLIT * NOUT * NS;

    mbd_prep_kernel<<<6400, 256, 0, stream>>>(inp, out, Abf, T, Tbf);
    mbd_gemm_kernel<<<512, 256, 0, stream>>>(Abf, Tbf, Mt);
    mbd_pair_kernel<<<BD * 2, 256, 0, stream>>>(Mt, out);
}

// Round 14
// 68.779 us; speedup vs baseline: 1.1411x; 1.0029x over previous
//
#include <hip/hip_runtime.h>
#include <hip/hip_bf16.h>

#define NS     256
#define FEAT   8192
#define BD     128
#define CD     16
#define NOUT   2048
#define OUTW   8320              // FEAT + BD
#define KSPLIT 16
#define KC     (FEAT / KSPLIT)   // 512
#define BK     32
#define NSTEP  (KC / BK)         // 16
#define BM     128
#define BN     128
#define NKT    (FEAT / BK)       // 256 global k-tiles (32-wide)

typedef float f32x4 __attribute__((ext_vector_type(4)));
typedef short bf16x8 __attribute__((ext_vector_type(8)));
typedef short bf16x4 __attribute__((ext_vector_type(4)));
typedef unsigned int u32;
typedef __attribute__((address_space(3))) u32 lds_u32;
typedef const __attribute__((address_space(1))) u32 gbl_u32;

__device__ __forceinline__ void gl_lds16(const void* g, void* l) {
    __builtin_amdgcn_global_load_lds((gbl_u32*)g, (lds_u32*)l, 16, 0, 0);
}

__device__ __forceinline__ bf16x4 cvt4(float a, float b, float c, float d) {
    union { __hip_bfloat162 h[2]; bf16x4 s; } u;
    u.h[0] = __float22bfloat162_rn(float2{a, b});
    u.h[1] = __float22bfloat162_rn(float2{c, d});
    return u.s;
}

__device__ __forceinline__ f32x4 bf4_to_f32(bf16x4 s) {
    f32x4 r;
    r.x = __uint_as_float(((u32)(unsigned short)s.x) << 16);
    r.y = __uint_as_float(((u32)(unsigned short)s.y) << 16);
    r.z = __uint_as_float(((u32)(unsigned short)s.z) << 16);
    r.w = __uint_as_float(((u32)(unsigned short)s.w) << 16);
    return r;
}

// ------------------------------------------------------------- prep (fused) -
// blocks 0..2303: copy inp -> out rows, zero o-cols, produce Abf (TILE-major
//                 [kt32][row][32k] -> gemm A-staging reads 1-KB contiguous).
// blocks 2304+:   transpose-cvt T f32 [k][n] -> Tbf bf16 TILE-major
//                 [kt32][n][32k] via 32x64 tiles -> writes 4-KB contiguous.
__global__ __launch_bounds__(256) void mbd_prep_kernel(const float* __restrict__ in,
                                                       float* __restrict__ out,
                                                       short* __restrict__ Abf,
                                                       const float* __restrict__ T,
                                                       short* __restrict__ Tbf) {
    __shared__ short ldsT[64 * 36];  // [n][k] pitch 36 (copy blocks ignore)
    const int bx = blockIdx.x, t = threadIdx.x;

    if (bx < 2304) {                 // ---- copy part (256 rows x 9 chunks)
        const int row = bx / 9;
        const int c4  = (bx - row * 9) * 256 + t;
        if (c4 < 2048) {
            f32x4 v = *(const f32x4*)(in + (size_t)row * FEAT + c4 * 4);
            *(f32x4*)(out + (size_t)row * OUTW + c4 * 4) = v;
            const int ktA  = c4 >> 3;            // global 32-k tile
            const int koff = (c4 & 7) * 4;
            *(bf16x4*)(Abf + (size_t)ktA * (NS * BK) + row * BK + koff) =
                cvt4(v.x, v.y, v.z, v.w);
        } else if (c4 < 2080) {
            *(f32x4*)(out + (size_t)row * OUTW + c4 * 4) = (f32x4){0.f, 0.f, 0.f, 0.f};
        }
        return;
    }

    // ---- transpose part: 32k x 64n tile per block
    const int b2   = bx - 2304;               // 0..8191
    const int kt32 = b2 >> 5;                 // 256 k-tiles
    const int nt0  = (b2 & 31) * 64;          // 32 n-tiles
    const int kt0  = kt32 * BK;

#pragma unroll
    for (int p = 0; p < 2; ++p) {
        int row = p * 16 + (t >> 4);          // k-row in tile 0..31
        int c4  = t & 15;                     // n-quad
        f32x4 v = *(const f32x4*)(T + (size_t)(kt0 + row) * NOUT + nt0 + c4 * 4);
        bf16x4 s = cvt4(v.x, v.y, v.z, v.w);
        ldsT[(c4 * 4 + 0) * 36 + row] = s.x;
        ldsT[(c4 * 4 + 1) * 36 + row] = s.y;
        ldsT[(c4 * 4 + 2) * 36 + row] = s.z;
        ldsT[(c4 * 4 + 3) * 36 + row] = s.w;
    }
    __syncthreads();

    const int n = t >> 2, part = t & 3;       // n 0..63, 8-k part
    *(bf16x8*)(Tbf + (size_t)kt32 * (NOUT * BK) + (nt0 + n) * BK + part * 8) =
        *(const bf16x8*)&ldsT[n * 36 + part * 8];
}

// ---------------------------------------------------------------- GEMM ------
// Mt[col][p][row] (bf16) = (Abf @ Tbf^T)^T per K-chunk p. R11-verified loop:
// gl_lds16 staging (source-baked XOR swizzle), ds_read_b128 frags, 16 MFMA,
// ONE barrier/step, zero in-loop VALU data work. Tile-major operands make
// every staging chunk a contiguous 1-KB global read.
__global__ __launch_bounds__(256, 4) void mbd_gemm_kernel(const short* __restrict__ Abf,
                                                          const short* __restrict__ Tbf,
                                                          short* __restrict__ Mt) {
    __shared__ __align__(16) short Als[2][BM * BK];   // 2 x 8 KB
    __shared__ __align__(16) short Bls[2][BN * BK];   // 2 x 8 KB

    const int tid = threadIdx.x, lane = tid & 63, l15 = lane & 15, w = tid >> 6;
    const int q = lane >> 4;
    const int wm = (w & 1) * 64, wn = (w >> 1) * 64;  // wave tile 64x64

    const int bx = blockIdx.x;
    const int kc = bx & 15;                  // bx%8 == kc%8 -> slabs L2-resident/XCD
    const int rest = bx >> 4;
    const int m0 = (rest & 1) * BM;
    const int n0 = (rest >> 1) * BN;

    // staging: 8 A-chunks + 8 B-chunks of 1 KB (16 rows x 64 B, contiguous);
    // stored quad s holds logical quad s^(r&3) (swizzle baked into source).
    const short* asrc[2]; const short* bsrc[2];
    int aofs[2], bofs[2];
#pragma unroll
    for (int u = 0; u < 2; ++u) {
        const int g = w * 2 + u;                       // chunk 0..7
        const int r = lane >> 2;                       // row-in-chunk 0..15
        const int lq = (lane & 3) ^ (r & 3);           // logical quad fetched
        asrc[u] = Abf + (size_t)(kc * NSTEP) * (NS * BK)
                      + (m0 + g * 16 + r) * BK + lq * 8;
        bsrc[u] = Tbf + (size_t)(kc * NSTEP) * (NOUT * BK)
                      + (n0 + g * 16 + r) * BK + lq * 8;
        aofs[u] = g * 512;
        bofs[u] = g * 512;
    }

    const int xq = (q ^ (l15 & 3)) * 8;
    int aro[4], bro[4];
#pragma unroll
    for (int mf = 0; mf < 4; ++mf) aro[mf] = (wm + mf * 16 + l15) * BK + xq;
#pragma unroll
    for (int nf = 0; nf < 4; ++nf) bro[nf] = (wn + nf * 16 + l15) * BK + xq;

    f32x4 acc[4][4];
#pragma unroll
    for (int mf = 0; mf < 4; ++mf)
#pragma unroll
        for (int nf = 0; nf < 4; ++nf) acc[mf][nf] = (f32x4){0.f, 0.f, 0.f, 0.f};

#pragma unroll
    for (int u = 0; u < 2; ++u) gl_lds16(asrc[u], &Als[0][aofs[u]]);
#pragma unroll
    for (int u = 0; u < 2; ++u) gl_lds16(bsrc[u], &Bls[0][bofs[u]]);
    __syncthreads();

    for (int kt = 0; kt < NSTEP; ++kt) {
        const int cur = kt & 1;
        if (kt + 1 < NSTEP) {   // fire-and-forget DMA into other buffer
#pragma unroll
            for (int u = 0; u < 2; ++u)
                gl_lds16(asrc[u] + (size_t)(kt + 1) * (NS * BK), &Als[cur ^ 1][aofs[u]]);
#pragma unroll
            for (int u = 0; u < 2; ++u)
                gl_lds16(bsrc[u] + (size_t)(kt + 1) * (NOUT * BK), &Bls[cur ^ 1][bofs[u]]);
        }
        bf16x8 af[4], bf[4];
#pragma unroll
        for (int mf = 0; mf < 4; ++mf) af[mf] = *(const bf16x8*)&Als[cur][aro[mf]];
#pragma unroll
        for (int nf = 0; nf < 4; ++nf) bf[nf] = *(const bf16x8*)&Bls[cur][bro[nf]];
        __builtin_amdgcn_s_setprio(1);
#pragma unroll
        for (int mf = 0; mf < 4; ++mf)
#pragma unroll
            for (int nf = 0; nf < 4; ++nf)
                acc[mf][nf] = __builtin_amdgcn_mfma_f32_16x16x32_bf16(
                    af[mf], bf[nf], acc[mf][nf], 0, 0, 0);
        __builtin_amdgcn_s_setprio(0);
        if (kt + 1 < NSTEP) __syncthreads();   // drains DMA; dbuf swap safe
    }

    // epilogue: C/D layout col = l&15, row = (l>>4)*4 + r  [m89-verified]
    // Mt[col][p][row]: pair's fold reads become fully contiguous.
    const int r0 = q * 4;
#pragma unroll
    for (int mf = 0; mf < 4; ++mf)
#pragma unroll
        for (int nf = 0; nf < 4; ++nf) {
            int col = n0 + wn + nf * 16 + l15;
            int row = m0 + wm + mf * 16 + r0;
            *(bf16x4*)&Mt[((size_t)col * KSPLIT + kc) * NS + row] =
                cvt4(acc[mf][nf].x, acc[mf][nf].y, acc[mf][nf].z, acc[mf][nf].w);
        }
}

// ---------------------------------------------------- pairwise (fused fold) -
// block (b, jhalf): o_part[i,b] = sum_{j in half} exp(-sum_c |M[i,c]-M[j,c]|).
// Mt[col][p][row]: block's fold region = 128 KB contiguous (16 c x 16 p x 512B).
__global__ __launch_bounds__(256) void mbd_pair_kernel(const short* __restrict__ Mt,
                                                       float* __restrict__ out) {
    const int b = blockIdx.x >> 1, jh = blockIdx.x & 1;
    const int t = threadIdx.x;
    __shared__ float ldsT[CD][NS];
    __shared__ float rows[NS][20];

#pragma unroll
    for (int u = 0; u < 2; ++u) {
        int chunk = t * 2 + u;                 // 0..511 (16 c x 32 row-chunks)
        int c  = chunk >> 5;
        int r8 = (chunk & 31) * 8;
        f32x4 lo = (f32x4){0.f, 0.f, 0.f, 0.f}, hi = lo;
#pragma unroll
        for (int p = 0; p < KSPLIT; ++p) {
            bf16x8 v = *(const bf16x8*)(Mt +
                ((size_t)(b * CD + c) * KSPLIT + p) * NS + r8);
            bf16x4 a, d;
            a.x = v[0]; a.y = v[1]; a.z = v[2]; a.w = v[3];
            d.x = v[4]; d.y = v[5]; d.z = v[6]; d.w = v[7];
            lo += bf4_to_f32(a);
            hi += bf4_to_f32(d);
        }
        *(f32x4*)&ldsT[c][r8]     = lo;
        *(f32x4*)&ldsT[c][r8 + 4] = hi;
    }
    __syncthreads();

    float my[16];
#pragma unroll
    for (int c = 0; c < 16; ++c) my[c] = ldsT[c][t];
#pragma unroll
    for (int c = 0; c < 16; ++c) rows[t][c] = my[c];
    __syncthreads();

    float o0 = 0.f, o1 = 0.f;
    const int jbase = jh * 128;
    for (int jj = 0; jj < 128; jj += 2) {
#pragma unroll
        for (int s = 0; s < 2; ++s) {
            const float* rp = &rows[jbase + jj + s][0];
            float d0 = 0.f, d1 = 0.f, d2 = 0.f, d3 = 0.f;
#pragma unroll
            for (int qq = 0; qq < 4; ++qq) {
                f32x4 r = *(const f32x4*)(rp + qq * 4);
                d0 += fabsf(my[qq * 4 + 0] - r.x);
                d1 += fabsf(my[qq * 4 + 1] - r.y);
                d2 += fabsf(my[qq * 4 + 2] - r.z);
                d3 += fabsf(my[qq * 4 + 3] - r.w);
            }
            float d = (d0 + d1) + (d2 + d3);
            if (s == 0) o0 += __expf(-d); else o1 += __expf(-d);
        }
    }
    // exactly two addends per address -> f32 add commutative -> deterministic
    atomicAdd(&out[(size_t)t * OUTW + FEAT + b], o0 + o1);
}

// ---------------------------------------------------------------- launch ----
extern "C" void kernel_launch(void* const* d_in, const int* in_sizes, int n_in,
                              void* d_out, int out_size, void* d_ws, size_t ws_size,
                              hipStream_t stream) {
    const float* inp = (const float*)d_in[0];
    const float* T   = (const float*)d_in[1];
    float* out = (float*)d_out;

    // ws: Abf 4 MiB | Mt 16 MiB | Tbf 32 MiB
    short* Abf = (short*)d_ws;
    short* Mt  = Abf + (size_t)NS * FEAT;
    short* Tbf = Mt + (size_t)KSPLIT * NOUT * NS;

    mbd_prep_kernel<<<2304 + 8192, 256, 0, stream>>>(inp, out, Abf, T, Tbf);
    mbd_gemm_kernel<<<512, 256, 0, stream>>>(Abf, Tbf, Mt);
    mbd_pair_kernel<<<BD * 2, 256, 0, stream>>>(Mt, out);
}